// Round 4
// baseline (74.098 us; speedup 1.0000x reference)
//
#include <hip/hip_runtime.h>
#include <hip/hip_bf16.h>

// WaveletConv: Haar DWT -> 4x (64x64 channel mix) -> inverse Haar, fused.
// B=8, C=64, H=256, W=256. Subband grid 128x128.
// R3: async global_load_lds staging of RAW x (64KB/block, zero VGPR cost,
//     16 DMAs in flight per wave), Haar computed in-register post-barrier
//     when building MFMA B-fragments. 0.5 Haar scale folded into weights.

using bf16x8  = __attribute__((ext_vector_type(8))) short;          // 8 bf16
using f32x4   = __attribute__((ext_vector_type(4))) float;          // MFMA acc

__device__ inline unsigned short f2bf(float v) {
    __hip_bfloat16 h = __float2bfloat16(v);
    return __builtin_bit_cast(unsigned short, h);
}

// ---------------------------------------------------------------------------
// Prep kernel: bake per-lane MFMA A-fragments (scaled by 0.5 = Haar factor)
// and sign-combined bias vectors into d_ws.
//   afrag element index: ((band*2 + ks)*4 + mt)*512 + lane*8 + i
//     holds bf16( 0.5 * W_band[o=16*mt+(lane&15)][c=32*ks+(lane>>4)*8+i] )
//   bcomb[d*64+o] = 0.5*(bLL + sH(di)*bLH + sW(dj)*bHL + sH*sW*bHH), d=di*2+dj
// ---------------------------------------------------------------------------
__global__ __launch_bounds__(256) void wvc_prep(
    const float* __restrict__ wLL, const float* __restrict__ bLL,
    const float* __restrict__ wLH, const float* __restrict__ bLH,
    const float* __restrict__ wHL, const float* __restrict__ bHL,
    const float* __restrict__ wHH, const float* __restrict__ bHH,
    unsigned short* __restrict__ afrag, float* __restrict__ bcomb)
{
    int t = threadIdx.x;
    const float* Ws[4] = {wLL, wLH, wHL, wHH};
    for (int idx = t; idx < 16384; idx += 256) {
        int i    = idx & 7;
        int lane = (idx >> 3) & 63;
        int mt   = (idx >> 9) & 3;
        int ks   = (idx >> 11) & 1;
        int band = (idx >> 12) & 3;
        int o = mt * 16 + (lane & 15);
        int c = ks * 32 + (lane >> 4) * 8 + i;
        afrag[idx] = f2bf(0.5f * Ws[band][o * 64 + c]);
    }
    if (t < 64) {
        float b0 = bLL[t], b1 = bLH[t], b2 = bHL[t], b3 = bHH[t];
        bcomb[0 * 64 + t] = 0.5f * (b0 + b1 + b2 + b3);
        bcomb[1 * 64 + t] = 0.5f * (b0 + b1 - b2 - b3);
        bcomb[2 * 64 + t] = 0.5f * (b0 - b1 + b2 - b3);
        bcomb[3 * 64 + t] = 0.5f * (b0 - b1 - b2 + b3);
    }
}

// ---------------------------------------------------------------------------
// Main kernel.
// grid = (2 j-tiles, 128 i-rows, 8 batches), block = 256 (4 waves).
// LDS: raw x tile [c][row][w] = 64 x 2 x 128 f32 = 64KB (linear, DMA-filled).
// ---------------------------------------------------------------------------
__global__ __launch_bounds__(256, 2) void wvc_main(
    const float* __restrict__ x,
    const unsigned short* __restrict__ afrag_g,
    const float* __restrict__ bcomb,
    float* __restrict__ out)
{
    __shared__ __align__(16) unsigned char lds_x[65536];  // [c][row][w] f32
    __shared__ __align__(16) float lds_bc[256];           // combined biases

    const int tid  = threadIdx.x;
    const int b    = blockIdx.z;
    const int irow = blockIdx.y;
    const int jt   = blockIdx.x;
    const int w0   = jt * 128;     // input w base (64 sites * 2)
    const int h0   = irow * 2;     // input h base
    const int l    = tid & 63;
    const int wv   = tid >> 6;

    // ---- async stage: wave wv DMAs channels wv*16 .. wv*16+15 into LDS ----
    // One global_load_lds per channel: lanes 0-31 -> row h0 (512B contig),
    // lanes 32-63 -> row h0+1 (512B contig); LDS dest = base + lane*16.
    {
        const float* g0 = x + (size_t)b * (64 * 65536)
                            + (size_t)(wv * 16) * 65536
                            + (size_t)(h0 + (l >> 5)) * 256 + w0 + (l & 31) * 4;
        unsigned char* lb = lds_x + wv * 16 * 1024;
        #pragma unroll
        for (int k = 0; k < 16; ++k) {
            __builtin_amdgcn_global_load_lds(
                (const __attribute__((address_space(1))) void*)(g0 + (size_t)k * 65536),
                (__attribute__((address_space(3))) void*)(lb + k * 1024),
                16, 0, 0);
        }
    }
    lds_bc[tid] = bcomb[tid];

    asm volatile("s_waitcnt vmcnt(0)" ::: "memory");
    __syncthreads();

    // ---- build B-fragments: LDS x -> Haar (no 0.5; folded in W) -> bf16 ----
    const int site = wv * 16 + (l & 15);   // 0..63 local site
    const int lg   = l >> 4;

    bf16x8 bfr[4][2];  // [band][ks]
    #pragma unroll
    for (int ks = 0; ks < 2; ++ks) {
        float2 p0[8], p1[8];
        #pragma unroll
        for (int i = 0; i < 8; ++i) {
            const unsigned char* base =
                lds_x + (size_t)(ks * 32 + lg * 8 + i) * 1024 + site * 8;
            p0[i] = *(const float2*)(base);        // row h0:   w=2s,2s+1
            p1[i] = *(const float2*)(base + 512);  // row h0+1
        }
        #pragma unroll
        for (int i = 0; i < 8; ++i) {
            float a = p0[i].x + p0[i].y, m = p0[i].x - p0[i].y;
            float c = p1[i].x + p1[i].y, d = p1[i].x - p1[i].y;
            bfr[0][ks][i] = (short)f2bf(a + c);
            bfr[1][ks][i] = (short)f2bf(a - c);
            bfr[2][ks][i] = (short)f2bf(m + d);
            bfr[3][ks][i] = (short)f2bf(m - d);
        }
    }

    // ---- MFMA: 4 bands x 2 ks x 4 mt, A-frags double-buffered from L2 ----
    const unsigned short* afb = afrag_g + (size_t)l * 8;

    f32x4 acc[4][4];  // [band][mt]
    #pragma unroll
    for (int bd = 0; bd < 4; ++bd)
        #pragma unroll
        for (int mt = 0; mt < 4; ++mt)
            acc[bd][mt] = (f32x4){0.f, 0.f, 0.f, 0.f};

    bf16x8 a[2][8];  // [buf][ks*4+mt]
    #pragma unroll
    for (int q = 0; q < 8; ++q)
        a[0][q] = *(const bf16x8*)(afb + (size_t)q * 512);

    #pragma unroll
    for (int bd = 0; bd < 4; ++bd) {
        if (bd < 3) {
            #pragma unroll
            for (int q = 0; q < 8; ++q)
                a[(bd + 1) & 1][q] = *(const bf16x8*)(afb + (size_t)((bd + 1) * 8 + q) * 512);
        }
        #pragma unroll
        for (int mt = 0; mt < 4; ++mt) {
            acc[bd][mt] = __builtin_amdgcn_mfma_f32_16x16x32_bf16(a[bd & 1][0 + mt], bfr[bd][0], acc[bd][mt], 0, 0, 0);
            acc[bd][mt] = __builtin_amdgcn_mfma_f32_16x16x32_bf16(a[bd & 1][4 + mt], bfr[bd][1], acc[bd][mt], 0, 0, 0);
        }
    }

    // ---- epilogue: inverse Haar recombine + bias, coalesced float2 stores ----
    const int wb = w0 + 2 * site;
    float* ob = out + (size_t)b * 64 * 65536 + (size_t)h0 * 256 + wb;
    #pragma unroll
    for (int mt = 0; mt < 4; ++mt) {
        const int ob0 = mt * 16 + lg * 4;
        f32x4 bc0 = *(const f32x4*)(&lds_bc[  0 + ob0]);
        f32x4 bc1 = *(const f32x4*)(&lds_bc[ 64 + ob0]);
        f32x4 bc2 = *(const f32x4*)(&lds_bc[128 + ob0]);
        f32x4 bc3 = *(const f32x4*)(&lds_bc[192 + ob0]);
        #pragma unroll
        for (int r = 0; r < 4; ++r) {
            float y0 = acc[0][mt][r];  // LL
            float y1 = acc[1][mt][r];  // LH (high-H)
            float y2 = acc[2][mt][r];  // HL (high-W)
            float y3 = acc[3][mt][r];  // HH
            float s01 = y0 + y1, d01 = y0 - y1;
            float s23 = y2 + y3, d23 = y2 - y3;
            float e00 = 0.5f * (s01 + s23) + bc0[r];
            float e01 = 0.5f * (s01 - s23) + bc1[r];
            float e10 = 0.5f * (d01 + d23) + bc2[r];
            float e11 = 0.5f * (d01 - d23) + bc3[r];
            float* po = ob + (size_t)(ob0 + r) * 65536;
            float2 v0; v0.x = e00; v0.y = e01;
            float2 v1; v1.x = e10; v1.y = e11;
            *(float2*)po         = v0;
            *(float2*)(po + 256) = v1;
        }
    }
}

extern "C" void kernel_launch(void* const* d_in, const int* in_sizes, int n_in,
                              void* d_out, int out_size, void* d_ws, size_t ws_size,
                              hipStream_t stream) {
    const float* x   = (const float*)d_in[0];
    const float* wLL = (const float*)d_in[1];
    const float* bLL = (const float*)d_in[2];
    const float* wLH = (const float*)d_in[3];
    const float* bLH = (const float*)d_in[4];
    const float* wHL = (const float*)d_in[5];
    const float* bHL = (const float*)d_in[6];
    const float* wHH = (const float*)d_in[7];
    const float* bHH = (const float*)d_in[8];
    float* out = (float*)d_out;

    unsigned short* afrag = (unsigned short*)d_ws;              // 32768 B
    float* bcomb = (float*)((char*)d_ws + 32768);               // 1024 B

    wvc_prep<<<1, 256, 0, stream>>>(wLL, bLL, wLH, bLH, wHL, bHL, wHH, bHH,
                                    afrag, bcomb);
    wvc_main<<<dim3(2, 128, 8), 256, 0, stream>>>(x, afrag, bcomb, out);
}

// Round 5
// 55.784 us; speedup vs baseline: 1.3283x; 1.3283x over previous
//
#include <hip/hip_runtime.h>
#include <hip/hip_bf16.h>

// WaveletConv: Haar DWT -> 4x (64x64 channel mix) -> inverse Haar, fused.
// B=8, C=64, H=256, W=256. Subband grid 128x128.
// R5: cross-tile software pipeline. 256 persistent blocks (1/CU, 512 thr,
//     8 waves), each runs 8 consecutive row-pair tiles with double-buffered
//     global_load_lds prefetch + counted vmcnt(8) + raw s_barrier, so every
//     CU keeps 64KB of reads in flight continuously (fixes the duty-cycle
//     stall that pinned R1-R4 at ~74us). A-frags persist in registers.

using bf16x8 = __attribute__((ext_vector_type(8))) short;   // 8 bf16
using f32x4  = __attribute__((ext_vector_type(4))) float;   // MFMA acc

__device__ inline unsigned short f2bf(float v) {
    __hip_bfloat16 h = __float2bfloat16(v);
    return __builtin_bit_cast(unsigned short, h);
}

// ---------------------------------------------------------------------------
// Prep kernel (64 blocks x 256 thr, one element each): bake per-lane MFMA
// A-fragments (scaled by 0.5 = Haar factor) and combined biases into d_ws.
//   afrag[((band*2+ks)*4+mt)*512 + lane*8 + i] =
//       bf16( 0.5 * W_band[o=16*mt+(lane&15)][c=32*ks+(lane>>4)*8+i] )
//   bcomb[d*64+o] = 0.5*(bLL + sH*bLH + sW*bHL + sH*sW*bHH), d=di*2+dj
// ---------------------------------------------------------------------------
__global__ __launch_bounds__(256) void wvc_prep(
    const float* __restrict__ wLL, const float* __restrict__ bLL,
    const float* __restrict__ wLH, const float* __restrict__ bLH,
    const float* __restrict__ wHL, const float* __restrict__ bHL,
    const float* __restrict__ wHH, const float* __restrict__ bHH,
    unsigned short* __restrict__ afrag, float* __restrict__ bcomb)
{
    const int idx  = blockIdx.x * 256 + threadIdx.x;  // 0..16383
    const int i    = idx & 7;
    const int lane = (idx >> 3) & 63;
    const int mt   = (idx >> 9) & 3;
    const int ks   = (idx >> 11) & 1;
    const int band = (idx >> 12) & 3;
    const float* Ws[4] = {wLL, wLH, wHL, wHH};
    const int o = mt * 16 + (lane & 15);
    const int c = ks * 32 + (lane >> 4) * 8 + i;
    afrag[idx] = f2bf(0.5f * Ws[band][o * 64 + c]);

    if (blockIdx.x == 0 && threadIdx.x < 64) {
        const int t = threadIdx.x;
        float b0 = bLL[t], b1 = bLH[t], b2 = bHL[t], b3 = bHH[t];
        bcomb[0 * 64 + t] = 0.5f * (b0 + b1 + b2 + b3);
        bcomb[1 * 64 + t] = 0.5f * (b0 + b1 - b2 - b3);
        bcomb[2 * 64 + t] = 0.5f * (b0 - b1 + b2 - b3);
        bcomb[3 * 64 + t] = 0.5f * (b0 - b1 - b2 + b3);
    }
}

// ---------------------------------------------------------------------------
// Main kernel. grid = 256 blocks, 512 threads (8 waves).
// Block blk: b = blk>>5, jt = (blk>>4)&1, ig = blk&15; tiles t=0..7 at
// irow = ig*8+t (h0 = 2*irow), w0 = 128*jt.
// LDS buf layout per tile: channel ch at ch*1024 + (ch>>3)*32 (pad breaks the
// lg-axis bank alias); 512B row h0 then 512B row h0+1.
// Waves 0-3: sites sg*16.., out-ch 0-31. Waves 4-7: same sites, out-ch 32-63.
// ---------------------------------------------------------------------------
#define NT 8
__global__ __launch_bounds__(512, 2) void wvc_main(
    const float* __restrict__ x,
    const unsigned short* __restrict__ afrag_g,
    const float* __restrict__ bcomb,
    float* __restrict__ out)
{
    __shared__ __align__(16) unsigned char lds_x[2][65792];  // 64KB + pad each
    __shared__ __align__(16) float lds_bc[256];

    const int tid = threadIdx.x;
    const int l   = tid & 63;
    const int wv  = tid >> 6;          // 0..7
    const int blk = blockIdx.x;
    const int b   = blk >> 5;
    const int jt  = (blk >> 4) & 1;
    const int ig  = blk & 15;
    const int w0  = jt * 128;

    const int sg   = wv & 3;
    const int m0   = (wv >> 2) * 2;    // mt base: 0 or 2
    const int site = sg * 16 + (l & 15);
    const int lg   = l >> 4;

    if (tid < 256) lds_bc[tid] = bcomb[tid];

    // ---- A-fragments: load once, persist in registers (16 x bf16x8) ----
    const unsigned short* afb = afrag_g + (size_t)l * 8;
    bf16x8 a[4][2][2];  // [band][ks][mtl]
    #pragma unroll
    for (int bd = 0; bd < 4; ++bd)
        #pragma unroll
        for (int ks = 0; ks < 2; ++ks)
            #pragma unroll
            for (int mtl = 0; mtl < 2; ++mtl)
                a[bd][ks][mtl] = *(const bf16x8*)(
                    afb + (size_t)((bd * 2 + ks) * 4 + m0 + mtl) * 512);

    // ---- DMA source/dest bases (wave wv owns channels wv*8..wv*8+7) ----
    const float* xb = x + (size_t)b * 4194304 + (size_t)(wv * 8) * 65536
                        + (size_t)(l >> 5) * 256 + w0 + (l & 31) * 4;
    unsigned char* lb[2] = { &lds_x[0][wv * 8 * 1024 + wv * 32],
                             &lds_x[1][wv * 8 * 1024 + wv * 32] };

    // prologue: prefetch tile 0 into buf 0
    {
        const float* g = xb + (size_t)(ig * 8 + 0) * 512;
        #pragma unroll
        for (int k = 0; k < 8; ++k)
            __builtin_amdgcn_global_load_lds(
                (const __attribute__((address_space(1))) void*)(g + (size_t)k * 65536),
                (__attribute__((address_space(3))) void*)(lb[0] + k * 1024),
                16, 0, 0);
    }
    asm volatile("s_waitcnt lgkmcnt(0)" ::: "memory");  // lds_bc visible

    for (int t = 0; t < NT; ++t) {
        // issue next tile's DMAs FIRST, then counted wait for current tile
        if (t + 1 < NT) {
            const float* g = xb + (size_t)(ig * 8 + t + 1) * 512;
            unsigned char* lbn = lb[(t + 1) & 1];
            #pragma unroll
            for (int k = 0; k < 8; ++k)
                __builtin_amdgcn_global_load_lds(
                    (const __attribute__((address_space(1))) void*)(g + (size_t)k * 65536),
                    (__attribute__((address_space(3))) void*)(lbn + k * 1024),
                    16, 0, 0);
            asm volatile("s_waitcnt vmcnt(8)" ::: "memory");  // drain tile t's 8 DMAs
        } else {
            asm volatile("s_waitcnt vmcnt(0)" ::: "memory");
        }
        __builtin_amdgcn_sched_barrier(0);
        __builtin_amdgcn_s_barrier();      // raw: no vmcnt(0) drain of prefetch
        __builtin_amdgcn_sched_barrier(0);

        const unsigned char* bx = lds_x[t & 1];

        // ---- B-fragments: LDS x -> Haar (0.5 folded into W) -> bf16 ----
        bf16x8 bfr[4][2];  // [band][ks]
        #pragma unroll
        for (int ks = 0; ks < 2; ++ks) {
            float2 p0[8], p1[8];
            #pragma unroll
            for (int i = 0; i < 8; ++i) {
                const int ch = ks * 32 + lg * 8 + i;
                const unsigned char* base =
                    bx + ch * 1024 + (ks * 4 + lg) * 32 + site * 8;
                p0[i] = *(const float2*)(base);        // row h0
                p1[i] = *(const float2*)(base + 512);  // row h0+1
            }
            #pragma unroll
            for (int i = 0; i < 8; ++i) {
                float aa = p0[i].x + p0[i].y, mm = p0[i].x - p0[i].y;
                float cc = p1[i].x + p1[i].y, dd = p1[i].x - p1[i].y;
                bfr[0][ks][i] = (short)f2bf(aa + cc);
                bfr[1][ks][i] = (short)f2bf(aa - cc);
                bfr[2][ks][i] = (short)f2bf(mm + dd);
                bfr[3][ks][i] = (short)f2bf(mm - dd);
            }
        }

        // ---- MFMA: 4 bands x 2 ks x 2 mt-local ----
        f32x4 acc[4][2];  // [band][mtl]
        #pragma unroll
        for (int bd = 0; bd < 4; ++bd)
            #pragma unroll
            for (int mtl = 0; mtl < 2; ++mtl)
                acc[bd][mtl] = (f32x4){0.f, 0.f, 0.f, 0.f};
        #pragma unroll
        for (int bd = 0; bd < 4; ++bd)
            #pragma unroll
            for (int ks = 0; ks < 2; ++ks)
                #pragma unroll
                for (int mtl = 0; mtl < 2; ++mtl)
                    acc[bd][mtl] = __builtin_amdgcn_mfma_f32_16x16x32_bf16(
                        a[bd][ks][mtl], bfr[bd][ks], acc[bd][mtl], 0, 0, 0);

        // ---- epilogue: inverse Haar recombine + bias, float2 stores ----
        const int h0 = (ig * 8 + t) * 2;
        float* ob = out + (size_t)b * 4194304 + (size_t)h0 * 256 + w0 + 2 * site;
        #pragma unroll
        for (int mtl = 0; mtl < 2; ++mtl) {
            const int ob0 = (m0 + mtl) * 16 + lg * 4;
            f32x4 bc0 = *(const f32x4*)(&lds_bc[  0 + ob0]);
            f32x4 bc1 = *(const f32x4*)(&lds_bc[ 64 + ob0]);
            f32x4 bc2 = *(const f32x4*)(&lds_bc[128 + ob0]);
            f32x4 bc3 = *(const f32x4*)(&lds_bc[192 + ob0]);
            #pragma unroll
            for (int r = 0; r < 4; ++r) {
                float y0 = acc[0][mtl][r];  // LL
                float y1 = acc[1][mtl][r];  // LH (high-H)
                float y2 = acc[2][mtl][r];  // HL (high-W)
                float y3 = acc[3][mtl][r];  // HH
                float s01 = y0 + y1, d01 = y0 - y1;
                float s23 = y2 + y3, d23 = y2 - y3;
                float e00 = 0.5f * (s01 + s23) + bc0[r];
                float e01 = 0.5f * (s01 - s23) + bc1[r];
                float e10 = 0.5f * (d01 + d23) + bc2[r];
                float e11 = 0.5f * (d01 - d23) + bc3[r];
                float* po = ob + (size_t)(ob0 + r) * 65536;
                float2 v0; v0.x = e00; v0.y = e01;
                float2 v1; v1.x = e10; v1.y = e11;
                *(float2*)po         = v0;
                *(float2*)(po + 256) = v1;
            }
        }

        __builtin_amdgcn_sched_barrier(0);
        __builtin_amdgcn_s_barrier();   // all waves done reading buf before
        __builtin_amdgcn_sched_barrier(0);  // next iter's DMAs overwrite it
    }
}

extern "C" void kernel_launch(void* const* d_in, const int* in_sizes, int n_in,
                              void* d_out, int out_size, void* d_ws, size_t ws_size,
                              hipStream_t stream) {
    const float* x   = (const float*)d_in[0];
    const float* wLL = (const float*)d_in[1];
    const float* bLL = (const float*)d_in[2];
    const float* wLH = (const float*)d_in[3];
    const float* bLH = (const float*)d_in[4];
    const float* wHL = (const float*)d_in[5];
    const float* bHL = (const float*)d_in[6];
    const float* wHH = (const float*)d_in[7];
    const float* bHH = (const float*)d_in[8];
    float* out = (float*)d_out;

    unsigned short* afrag = (unsigned short*)d_ws;   // 32768 B
    float* bcomb = (float*)((char*)d_ws + 32768);    // 1024 B

    wvc_prep<<<64, 256, 0, stream>>>(wLL, bLL, wLH, bLH, wHL, bHL, wHH, bHH,
                                     afrag, bcomb);
    wvc_main<<<256, 512, 0, stream>>>(x, afrag, bcomb, out);
}

// Round 6
// 54.833 us; speedup vs baseline: 1.3513x; 1.0173x over previous
//
#include <hip/hip_runtime.h>
#include <hip/hip_bf16.h>

// WaveletConv: Haar DWT -> 4x (64x64 channel mix) -> inverse Haar, fused.
// B=8, C=64, H=256, W=256. Subband grid 128x128.
// R6: (a) store-exclusion vmcnt counting (vmcnt(24) steady state: previous
//     epilogue stores may stay in flight across the tile wait), (b) two
//     independent 4-wave blocks per CU (32-site tiles, 67KB LDS each) so one
//     block's compute covers the other's barrier/wait stalls.

using bf16x8 = __attribute__((ext_vector_type(8))) short;   // 8 bf16
using f32x4  = __attribute__((ext_vector_type(4))) float;   // MFMA acc

__device__ inline unsigned short f2bf(float v) {
    __hip_bfloat16 h = __float2bfloat16(v);
    return __builtin_bit_cast(unsigned short, h);
}

// ---------------------------------------------------------------------------
// Prep kernel (64 blocks x 256 thr): bake per-lane MFMA A-fragments (scaled
// by 0.5 = Haar factor) and combined biases into d_ws.
//   afrag[((band*2+ks)*4+mt)*512 + lane*8 + i] =
//       bf16( 0.5 * W_band[o=16*mt+(lane&15)][c=32*ks+(lane>>4)*8+i] )
//   bcomb[d*64+o] = 0.5*(bLL + sH*bLH + sW*bHL + sH*sW*bHH), d=di*2+dj
// ---------------------------------------------------------------------------
__global__ __launch_bounds__(256) void wvc_prep(
    const float* __restrict__ wLL, const float* __restrict__ bLL,
    const float* __restrict__ wLH, const float* __restrict__ bLH,
    const float* __restrict__ wHL, const float* __restrict__ bHL,
    const float* __restrict__ wHH, const float* __restrict__ bHH,
    unsigned short* __restrict__ afrag, float* __restrict__ bcomb)
{
    const int idx  = blockIdx.x * 256 + threadIdx.x;  // 0..16383
    const int i    = idx & 7;
    const int lane = (idx >> 3) & 63;
    const int mt   = (idx >> 9) & 3;
    const int ks   = (idx >> 11) & 1;
    const int band = (idx >> 12) & 3;
    const float* Ws[4] = {wLL, wLH, wHL, wHH};
    const int o = mt * 16 + (lane & 15);
    const int c = ks * 32 + (lane >> 4) * 8 + i;
    afrag[idx] = f2bf(0.5f * Ws[band][o * 64 + c]);

    if (blockIdx.x == 0 && threadIdx.x < 64) {
        const int t = threadIdx.x;
        float b0 = bLL[t], b1 = bLH[t], b2 = bHL[t], b3 = bHH[t];
        bcomb[0 * 64 + t] = 0.5f * (b0 + b1 + b2 + b3);
        bcomb[1 * 64 + t] = 0.5f * (b0 + b1 - b2 - b3);
        bcomb[2 * 64 + t] = 0.5f * (b0 - b1 + b2 - b3);
        bcomb[3 * 64 + t] = 0.5f * (b0 - b1 - b2 + b3);
    }
}

// ---------------------------------------------------------------------------
// Main kernel. grid = 512 blocks, 256 threads (4 waves), 2 blocks/CU.
// Block blk: b = blk>>6, jq = (blk>>4)&3, ig = blk&15; tiles t=0..7 at
// irow = ig*8+t (h0 = 2*irow), w0 = 64*jq (floats).
// Tile in LDS: 64 ch x 2 rows x 64 w f32; off(ch,row,w) =
//   ch*512 + (ch>>3)*32 + row*256 + w*4   (pad breaks lg-axis bank alias).
// Wave wv: sg = wv&1 (sites sg*16..+15), m0 = (wv>>1)*2 (out-ch pair base).
// Per tile per wave: 8 DMAs in, 16 MFMAs, 16 8B stores out.
// vmcnt ledger at the tile-t wait: [DMA(t)=8][stores(t-1)=16][DMA(t+1)=8]
//   -> wait vmcnt(24) guarantees DMA(t) retired w/o draining stores.
// ---------------------------------------------------------------------------
#define NT 8
__global__ __launch_bounds__(256, 2) void wvc_main(
    const float* __restrict__ x,
    const unsigned short* __restrict__ afrag_g,
    const float* __restrict__ bcomb,
    float* __restrict__ out)
{
    __shared__ __align__(64) unsigned char lds_x[2][33024];  // 32KB + pads
    __shared__ __align__(16) float lds_bc[256];

    const int tid = threadIdx.x;
    const int l   = tid & 63;
    const int wv  = tid >> 6;          // 0..3
    const int blk = blockIdx.x;
    const int b   = blk >> 6;
    const int jq  = (blk >> 4) & 3;
    const int ig  = blk & 15;
    const int w0  = jq * 64;           // float offset in W

    const int sg   = wv & 1;
    const int m0   = (wv >> 1) * 2;    // mt base: 0 or 2
    const int site = sg * 16 + (l & 15);   // 0..31
    const int lg   = l >> 4;

    lds_bc[tid] = bcomb[tid];

    // ---- A-fragments: load once, persist in registers (16 x bf16x8) ----
    const unsigned short* afb = afrag_g + (size_t)l * 8;
    bf16x8 a[4][2][2];  // [band][ks][mtl]
    #pragma unroll
    for (int bd = 0; bd < 4; ++bd)
        #pragma unroll
        for (int ks = 0; ks < 2; ++ks)
            #pragma unroll
            for (int mtl = 0; mtl < 2; ++mtl)
                a[bd][ks][mtl] = *(const bf16x8*)(
                    afb + (size_t)((bd * 2 + ks) * 4 + m0 + mtl) * 512);

    // ---- DMA bases: wave wv stages channels wv*16 .. wv*16+15 ----
    // DMA k covers channels (wv*16+2k, wv*16+2k+1); per-lane global source:
    //   ch += l>>5, row = (l>>4)&1, w = (l&15)*4 ; LDS dest = base + l*16.
    const float* xb = x + (size_t)b * 4194304
                        + (size_t)(wv * 16 + (l >> 5)) * 65536
                        + (size_t)((l >> 4) & 1) * 256 + w0 + (l & 15) * 4;
    const int lbo = (wv * 16) * 512 + (wv * 2) * 32;  // LDS offset of wave's chans

    // prologue: prefetch tile 0 into buf 0
    {
        const float* g = xb + (size_t)(ig * 8 + 0) * 512;
        unsigned char* lbn = &lds_x[0][lbo];
        #pragma unroll
        for (int k = 0; k < 8; ++k)
            __builtin_amdgcn_global_load_lds(
                (const __attribute__((address_space(1))) void*)(g + (size_t)(2 * k) * 65536),
                (__attribute__((address_space(3))) void*)(lbn + k * 1024 + (k >> 2) * 32),
                16, 0, 0);
    }
    asm volatile("s_waitcnt lgkmcnt(0)" ::: "memory");  // lds_bc visible

    for (int t = 0; t < NT; ++t) {
        // issue next tile's DMAs FIRST, then counted wait for current tile
        if (t + 1 < NT) {
            const float* g = xb + (size_t)(ig * 8 + t + 1) * 512;
            unsigned char* lbn = &lds_x[(t + 1) & 1][lbo];
            #pragma unroll
            for (int k = 0; k < 8; ++k)
                __builtin_amdgcn_global_load_lds(
                    (const __attribute__((address_space(1))) void*)(g + (size_t)(2 * k) * 65536),
                    (__attribute__((address_space(3))) void*)(lbn + k * 1024 + (k >> 2) * 32),
                    16, 0, 0);
        }
        // vmcnt ledger: t==0 -> only DMA(0)+DMA(1) outstanding, need DMA(0):
        //   vmcnt(8). 0<t<NT-1 -> vmcnt(24). t==NT-1 -> no new DMA: vmcnt(16).
        if (t == 0)            asm volatile("s_waitcnt vmcnt(8)"  ::: "memory");
        else if (t + 1 < NT)   asm volatile("s_waitcnt vmcnt(24)" ::: "memory");
        else                   asm volatile("s_waitcnt vmcnt(16)" ::: "memory");
        __builtin_amdgcn_sched_barrier(0);
        __builtin_amdgcn_s_barrier();      // raw: no vmcnt(0) drain of prefetch
        __builtin_amdgcn_sched_barrier(0);

        const unsigned char* bx = lds_x[t & 1];

        // ---- B-fragments: LDS x -> Haar (0.5 folded into W) -> bf16 ----
        bf16x8 bfr[4][2];  // [band][ks]
        #pragma unroll
        for (int ks = 0; ks < 2; ++ks) {
            float2 p0[8], p1[8];
            #pragma unroll
            for (int i = 0; i < 8; ++i) {
                const unsigned char* base =
                    bx + (size_t)(ks * 32 + lg * 8 + i) * 512
                       + (ks * 4 + lg) * 32 + site * 8;
                p0[i] = *(const float2*)(base);        // row h0
                p1[i] = *(const float2*)(base + 256);  // row h0+1
            }
            #pragma unroll
            for (int i = 0; i < 8; ++i) {
                float aa = p0[i].x + p0[i].y, mm = p0[i].x - p0[i].y;
                float cc = p1[i].x + p1[i].y, dd = p1[i].x - p1[i].y;
                bfr[0][ks][i] = (short)f2bf(aa + cc);
                bfr[1][ks][i] = (short)f2bf(aa - cc);
                bfr[2][ks][i] = (short)f2bf(mm + dd);
                bfr[3][ks][i] = (short)f2bf(mm - dd);
            }
        }

        // ---- MFMA: 4 bands x 2 ks x 2 mt-local ----
        f32x4 acc[4][2];  // [band][mtl]
        #pragma unroll
        for (int bd = 0; bd < 4; ++bd)
            #pragma unroll
            for (int mtl = 0; mtl < 2; ++mtl)
                acc[bd][mtl] = (f32x4){0.f, 0.f, 0.f, 0.f};
        #pragma unroll
        for (int bd = 0; bd < 4; ++bd)
            #pragma unroll
            for (int ks = 0; ks < 2; ++ks)
                #pragma unroll
                for (int mtl = 0; mtl < 2; ++mtl)
                    acc[bd][mtl] = __builtin_amdgcn_mfma_f32_16x16x32_bf16(
                        a[bd][ks][mtl], bfr[bd][ks], acc[bd][mtl], 0, 0, 0);

        // ---- epilogue: inverse Haar recombine + bias, 16 float2 stores ----
        const int h0 = (ig * 8 + t) * 2;
        float* ob = out + (size_t)b * 4194304 + (size_t)h0 * 256 + w0 + 2 * site;
        #pragma unroll
        for (int mtl = 0; mtl < 2; ++mtl) {
            const int ob0 = (m0 + mtl) * 16 + lg * 4;
            f32x4 bc0 = *(const f32x4*)(&lds_bc[  0 + ob0]);
            f32x4 bc1 = *(const f32x4*)(&lds_bc[ 64 + ob0]);
            f32x4 bc2 = *(const f32x4*)(&lds_bc[128 + ob0]);
            f32x4 bc3 = *(const f32x4*)(&lds_bc[192 + ob0]);
            #pragma unroll
            for (int r = 0; r < 4; ++r) {
                float y0 = acc[0][mtl][r];  // LL
                float y1 = acc[1][mtl][r];  // LH (high-H)
                float y2 = acc[2][mtl][r];  // HL (high-W)
                float y3 = acc[3][mtl][r];  // HH
                float s01 = y0 + y1, d01 = y0 - y1;
                float s23 = y2 + y3, d23 = y2 - y3;
                float e00 = 0.5f * (s01 + s23) + bc0[r];
                float e01 = 0.5f * (s01 - s23) + bc1[r];
                float e10 = 0.5f * (d01 + d23) + bc2[r];
                float e11 = 0.5f * (d01 - d23) + bc3[r];
                float* po = ob + (size_t)(ob0 + r) * 65536;
                float2 v0; v0.x = e00; v0.y = e01;
                float2 v1; v1.x = e10; v1.y = e11;
                *(float2*)po         = v0;
                *(float2*)(po + 256) = v1;
            }
        }

        __builtin_amdgcn_sched_barrier(0);
        __builtin_amdgcn_s_barrier();   // all waves done reading buf before
        __builtin_amdgcn_sched_barrier(0);  // next iter's DMAs overwrite it
    }
}

extern "C" void kernel_launch(void* const* d_in, const int* in_sizes, int n_in,
                              void* d_out, int out_size, void* d_ws, size_t ws_size,
                              hipStream_t stream) {
    const float* x   = (const float*)d_in[0];
    const float* wLL = (const float*)d_in[1];
    const float* bLL = (const float*)d_in[2];
    const float* wLH = (const float*)d_in[3];
    const float* bLH = (const float*)d_in[4];
    const float* wHL = (const float*)d_in[5];
    const float* bHL = (const float*)d_in[6];
    const float* wHH = (const float*)d_in[7];
    const float* bHH = (const float*)d_in[8];
    float* out = (float*)d_out;

    unsigned short* afrag = (unsigned short*)d_ws;   // 32768 B
    float* bcomb = (float*)((char*)d_ws + 32768);    // 1024 B

    wvc_prep<<<64, 256, 0, stream>>>(wLL, bLL, wLH, bLH, wHL, bHL, wHH, bHH,
                                     afrag, bcomb);
    wvc_main<<<512, 256, 0, stream>>>(x, afrag, bcomb, out);
}

// Round 7
// 52.663 us; speedup vs baseline: 1.4070x; 1.0412x over previous
//
#include <hip/hip_runtime.h>
#include <hip/hip_bf16.h>

// WaveletConv: Haar DWT -> 4x (64x64 channel mix) -> inverse Haar, fused.
// B=8, C=64, H=256, W=256. Subband grid 128x128.
// R7: depth-2 read pipeline (3 LDS buffers, 64KB of reads in flight per CU
//     continuously), 1 block/CU x 8 waves x 16 tiles, store-exclusion vmcnt,
//     non-temporal output stores (preserve x in L3, reduce L2 write thrash).

using bf16x8 = __attribute__((ext_vector_type(8))) short;   // 8 bf16
using f32x4  = __attribute__((ext_vector_type(4))) float;   // MFMA acc
using f32x2  = __attribute__((ext_vector_type(2))) float;

__device__ inline unsigned short f2bf(float v) {
    __hip_bfloat16 h = __float2bfloat16(v);
    return __builtin_bit_cast(unsigned short, h);
}

// ---------------------------------------------------------------------------
// Prep kernel (64 blocks x 256 thr): bake per-lane MFMA A-fragments (scaled
// by 0.5 = Haar factor) and combined biases into d_ws.
//   afrag[((band*2+ks)*4+mt)*512 + lane*8 + i] =
//       bf16( 0.5 * W_band[o=16*mt+(lane&15)][c=32*ks+(lane>>4)*8+i] )
//   bcomb[d*64+o] = 0.5*(bLL + sH*bLH + sW*bHL + sH*sW*bHH), d=di*2+dj
// ---------------------------------------------------------------------------
__global__ __launch_bounds__(256) void wvc_prep(
    const float* __restrict__ wLL, const float* __restrict__ bLL,
    const float* __restrict__ wLH, const float* __restrict__ bLH,
    const float* __restrict__ wHL, const float* __restrict__ bHL,
    const float* __restrict__ wHH, const float* __restrict__ bHH,
    unsigned short* __restrict__ afrag, float* __restrict__ bcomb)
{
    const int idx  = blockIdx.x * 256 + threadIdx.x;  // 0..16383
    const int i    = idx & 7;
    const int lane = (idx >> 3) & 63;
    const int mt   = (idx >> 9) & 3;
    const int ks   = (idx >> 11) & 1;
    const int band = (idx >> 12) & 3;
    const float* Ws[4] = {wLL, wLH, wHL, wHH};
    const int o = mt * 16 + (lane & 15);
    const int c = ks * 32 + (lane >> 4) * 8 + i;
    afrag[idx] = f2bf(0.5f * Ws[band][o * 64 + c]);

    if (blockIdx.x == 0 && threadIdx.x < 64) {
        const int t = threadIdx.x;
        float b0 = bLL[t], b1 = bLH[t], b2 = bHL[t], b3 = bHH[t];
        bcomb[0 * 64 + t] = 0.5f * (b0 + b1 + b2 + b3);
        bcomb[1 * 64 + t] = 0.5f * (b0 + b1 - b2 - b3);
        bcomb[2 * 64 + t] = 0.5f * (b0 - b1 + b2 - b3);
        bcomb[3 * 64 + t] = 0.5f * (b0 - b1 - b2 + b3);
    }
}

// ---------------------------------------------------------------------------
// Main kernel. grid = 256 blocks, 512 threads (8 waves), 1 block/CU.
// Block blk: b = blk>>5, jq = (blk>>3)&3, ih = blk&7; tiles t=0..15 at
// irow = ih*16+t (h0 = 2*irow), w0 = 64*jq (floats).
// Tile in LDS: 64 ch x 2 rows x 64 w f32; off(ch,row,w) =
//   ch*512 + (ch>>3)*32 + row*256 + w*4.   3 buffers (depth-2 prefetch).
// Wave wv (0..7): stages channels wv*8..wv*8+7 (4 DMAs of 2ch x 2rows x 256B);
//   computes sites sg*16..+15 (sg=wv&1) x out-ch mt*16..+15 (mt=wv>>1).
// Per tile per wave: 4 DMAs in, 8 MFMAs, 8 nt f32x2 stores out.
// vmcnt ledger at tile-t wait (batches: DMA=4, stores=8):
//   n = (t>=1 ? 8 : 0) + 4*(t+1<NT) + 4*(t+2<NT)
// ---------------------------------------------------------------------------
#define NT 16
__global__ __launch_bounds__(512, 1) void wvc_main(
    const float* __restrict__ x,
    const unsigned short* __restrict__ afrag_g,
    const float* __restrict__ bcomb,
    float* __restrict__ out)
{
    __shared__ __align__(64) unsigned char lds_x[3][33024];  // 32KB + pads
    __shared__ __align__(16) float lds_bc[256];

    const int tid = threadIdx.x;
    const int l   = tid & 63;
    const int wv  = tid >> 6;          // 0..7
    const int blk = blockIdx.x;
    const int b   = blk >> 5;
    const int jq  = (blk >> 3) & 3;
    const int ih  = blk & 7;
    const int w0  = jq * 64;           // float offset in W

    const int sg   = wv & 1;
    const int mt   = wv >> 1;          // 0..3
    const int site = sg * 16 + (l & 15);   // 0..31
    const int lg   = l >> 4;

    if (tid < 256) lds_bc[tid] = bcomb[tid];

    // ---- A-fragments: load once, persist in registers (8 x bf16x8) ----
    const unsigned short* afb = afrag_g + (size_t)l * 8;
    bf16x8 a[4][2];  // [band][ks]
    #pragma unroll
    for (int bd = 0; bd < 4; ++bd)
        #pragma unroll
        for (int ks = 0; ks < 2; ++ks)
            a[bd][ks] = *(const bf16x8*)(
                afb + (size_t)((bd * 2 + ks) * 4 + mt) * 512);

    // ---- DMA bases: wave wv stages channels wv*8 .. wv*8+7 ----
    // DMA k covers channels (wv*8+2k, wv*8+2k+1); per-lane global source:
    //   ch += l>>5, row = (l>>4)&1, w = (l&15)*4 ; LDS dest = base + l*16.
    const float* xb = x + (size_t)b * 4194304
                        + (size_t)(wv * 8 + (l >> 5)) * 65536
                        + (size_t)((l >> 4) & 1) * 256 + w0 + (l & 15) * 4;
    const int lbo = wv * 4096 + wv * 32;   // LDS offset of wave's channels

    // prologue: prefetch tiles 0,1 into bufs 0,1
    #pragma unroll
    for (int pt = 0; pt < 2; ++pt) {
        const float* g = xb + (size_t)(ih * 16 + pt) * 512;
        unsigned char* lbn = &lds_x[pt][lbo];
        #pragma unroll
        for (int k = 0; k < 4; ++k)
            __builtin_amdgcn_global_load_lds(
                (const __attribute__((address_space(1))) void*)(g + (size_t)(2 * k) * 65536),
                (__attribute__((address_space(3))) void*)(lbn + k * 1024),
                16, 0, 0);
    }
    asm volatile("s_waitcnt lgkmcnt(0)" ::: "memory");  // lds_bc visible

    #pragma unroll
    for (int t = 0; t < NT; ++t) {
        // issue tile t+2's DMAs FIRST, then counted wait for tile t
        if (t + 2 < NT) {
            const float* g = xb + (size_t)(ih * 16 + t + 2) * 512;
            unsigned char* lbn = &lds_x[(t + 2) % 3][lbo];
            #pragma unroll
            for (int k = 0; k < 4; ++k)
                __builtin_amdgcn_global_load_lds(
                    (const __attribute__((address_space(1))) void*)(g + (size_t)(2 * k) * 65536),
                    (__attribute__((address_space(3))) void*)(lbn + k * 1024),
                    16, 0, 0);
        }
        // ledger: stores(t-1)=8 (t>=1) + 4 per future DMA batch in queue
        if (t == 0)            asm volatile("s_waitcnt vmcnt(8)"  ::: "memory");
        else if (t + 2 < NT)   asm volatile("s_waitcnt vmcnt(16)" ::: "memory");
        else if (t + 1 < NT)   asm volatile("s_waitcnt vmcnt(12)" ::: "memory");
        else                   asm volatile("s_waitcnt vmcnt(8)"  ::: "memory");
        __builtin_amdgcn_sched_barrier(0);
        __builtin_amdgcn_s_barrier();      // raw: no vmcnt(0) drain of prefetch
        __builtin_amdgcn_sched_barrier(0);

        const unsigned char* bx = lds_x[t % 3];

        // ---- B-fragments: LDS x -> Haar (0.5 folded into W) -> bf16 ----
        bf16x8 bfr[4][2];  // [band][ks]
        #pragma unroll
        for (int ks = 0; ks < 2; ++ks) {
            float2 p0[8], p1[8];
            #pragma unroll
            for (int i = 0; i < 8; ++i) {
                const unsigned char* base =
                    bx + (size_t)(ks * 32 + lg * 8 + i) * 512
                       + (ks * 4 + lg) * 32 + site * 8;
                p0[i] = *(const float2*)(base);        // row h0
                p1[i] = *(const float2*)(base + 256);  // row h0+1
            }
            #pragma unroll
            for (int i = 0; i < 8; ++i) {
                float aa = p0[i].x + p0[i].y, mm = p0[i].x - p0[i].y;
                float cc = p1[i].x + p1[i].y, dd = p1[i].x - p1[i].y;
                bfr[0][ks][i] = (short)f2bf(aa + cc);
                bfr[1][ks][i] = (short)f2bf(aa - cc);
                bfr[2][ks][i] = (short)f2bf(mm + dd);
                bfr[3][ks][i] = (short)f2bf(mm - dd);
            }
        }

        // ---- MFMA: 4 bands x 2 ks, single mt per wave ----
        f32x4 acc[4];
        #pragma unroll
        for (int bd = 0; bd < 4; ++bd)
            acc[bd] = (f32x4){0.f, 0.f, 0.f, 0.f};
        #pragma unroll
        for (int bd = 0; bd < 4; ++bd)
            #pragma unroll
            for (int ks = 0; ks < 2; ++ks)
                acc[bd] = __builtin_amdgcn_mfma_f32_16x16x32_bf16(
                    a[bd][ks], bfr[bd][ks], acc[bd], 0, 0, 0);

        // ---- epilogue: inverse Haar recombine + bias, 8 nt f32x2 stores ----
        const int h0 = (ih * 16 + t) * 2;
        float* ob = out + (size_t)b * 4194304 + (size_t)h0 * 256 + w0 + 2 * site;
        const int ob0 = mt * 16 + lg * 4;
        f32x4 bc0 = *(const f32x4*)(&lds_bc[  0 + ob0]);
        f32x4 bc1 = *(const f32x4*)(&lds_bc[ 64 + ob0]);
        f32x4 bc2 = *(const f32x4*)(&lds_bc[128 + ob0]);
        f32x4 bc3 = *(const f32x4*)(&lds_bc[192 + ob0]);
        #pragma unroll
        for (int r = 0; r < 4; ++r) {
            float y0 = acc[0][r];  // LL
            float y1 = acc[1][r];  // LH (high-H)
            float y2 = acc[2][r];  // HL (high-W)
            float y3 = acc[3][r];  // HH
            float s01 = y0 + y1, d01 = y0 - y1;
            float s23 = y2 + y3, d23 = y2 - y3;
            f32x2 v0; v0[0] = 0.5f * (s01 + s23) + bc0[r];
                      v0[1] = 0.5f * (s01 - s23) + bc1[r];
            f32x2 v1; v1[0] = 0.5f * (d01 + d23) + bc2[r];
                      v1[1] = 0.5f * (d01 - d23) + bc3[r];
            float* po = ob + (size_t)(ob0 + r) * 65536;
            __builtin_nontemporal_store(v0, (f32x2*)po);
            __builtin_nontemporal_store(v1, (f32x2*)(po + 256));
        }

        __builtin_amdgcn_sched_barrier(0);
        __builtin_amdgcn_s_barrier();   // all waves done reading buf[t%3]
        __builtin_amdgcn_sched_barrier(0);  // before iter t+1 overwrites it
    }
}

extern "C" void kernel_launch(void* const* d_in, const int* in_sizes, int n_in,
                              void* d_out, int out_size, void* d_ws, size_t ws_size,
                              hipStream_t stream) {
    const float* x   = (const float*)d_in[0];
    const float* wLL = (const float*)d_in[1];
    const float* bLL = (const float*)d_in[2];
    const float* wLH = (const float*)d_in[3];
    const float* bLH = (const float*)d_in[4];
    const float* wHL = (const float*)d_in[5];
    const float* bHL = (const float*)d_in[6];
    const float* wHH = (const float*)d_in[7];
    const float* bHH = (const float*)d_in[8];
    float* out = (float*)d_out;

    unsigned short* afrag = (unsigned short*)d_ws;   // 32768 B
    float* bcomb = (float*)((char*)d_ws + 32768);    // 1024 B

    wvc_prep<<<64, 256, 0, stream>>>(wLL, bLL, wLH, bLH, wHL, bHL, wHH, bHH,
                                     afrag, bcomb);
    wvc_main<<<256, 512, 0, stream>>>(x, afrag, bcomb, out);
}